// Round 1
// baseline (1123.852 us; speedup 1.0000x reference)
//
#include <hip/hip_runtime.h>
#include <math.h>

#define N_NODES   2000000
#define N_MOVABLE 1500000
#define N_FILLER  400000
#define N_NETS    1500000
#define N_PINS    (N_NETS * 4)
#define NB        512                  // bins per axis
#define ND        513                  // diff-map dimension (NB+1)
#define MAPSZ     (ND * ND)

__device__ __forceinline__ float binw() { return 1000.0f / 512.0f; }  // exact: 1.953125

__device__ __forceinline__ int bin_idx(float v) {
    // matches jnp: clip(floor(v / BIN_W), 0, 511) -> int32   (XL == 0)
    float b = floorf(v / binw());
    b = fminf(fmaxf(b, 0.0f), 511.0f);
    return (int)b;
}

// ---------------------------------------------------------------------------
// Stage 1: per-net bbox -> density -> 4-corner difference-map atomics
// ---------------------------------------------------------------------------
__global__ void net_kernel(const float* __restrict__ pin_pos,
                           const int*  __restrict__ flat_netpin,
                           float* __restrict__ Dh, float* __restrict__ Dv) {
    int n = blockIdx.x * blockDim.x + threadIdx.x;
    if (n >= N_NETS) return;

    int4 fp = *reinterpret_cast<const int4*>(flat_netpin + 4 * n);

    float px0 = pin_pos[fp.x], px1 = pin_pos[fp.y];
    float px2 = pin_pos[fp.z], px3 = pin_pos[fp.w];
    float py0 = pin_pos[N_PINS + fp.x], py1 = pin_pos[N_PINS + fp.y];
    float py2 = pin_pos[N_PINS + fp.z], py3 = pin_pos[N_PINS + fp.w];

    float xl = fminf(fminf(px0, px1), fminf(px2, px3));
    float xh = fmaxf(fmaxf(px0, px1), fmaxf(px2, px3));
    float yl = fminf(fminf(py0, py1), fminf(py2, py3));
    float yh = fmaxf(fmaxf(py0, py1), fmaxf(py2, py3));

    float bw = xh - xl, bh = yh - yl;
    float barea = fmaxf(bw * bh, 1e-6f);
    // fold the /1.5 capacity division in here so util = map value directly
    float vh = (bw / barea) * (1.0f / 1.5f);
    float vv = (bh / barea) * (1.0f / 1.5f);

    int blx = bin_idx(xl), bhx = bin_idx(xh);
    int bly = bin_idx(yl), bhy = bin_idx(yh);

    int i00 = blx * ND + bly;
    int i10 = (bhx + 1) * ND + bly;
    int i01 = blx * ND + (bhy + 1);
    int i11 = (bhx + 1) * ND + (bhy + 1);

    atomicAdd(&Dh[i00],  vh);
    atomicAdd(&Dh[i10], -vh);
    atomicAdd(&Dh[i01], -vh);
    atomicAdd(&Dh[i11],  vh);

    atomicAdd(&Dv[i00],  vv);
    atomicAdd(&Dv[i10], -vv);
    atomicAdd(&Dv[i01], -vv);
    atomicAdd(&Dv[i11],  vv);
}

// ---------------------------------------------------------------------------
// Stage 2: 2D prefix sums (in-place). Maps are contiguous: D, D+MAPSZ.
// ---------------------------------------------------------------------------
__global__ void cumsum_x_kernel(float* __restrict__ D) {
    int tid = blockIdx.x * blockDim.x + threadIdx.x;
    if (tid >= 2 * ND) return;
    float* M = D + (tid / ND) * MAPSZ;
    int y = tid % ND;
    float acc = 0.0f;
    for (int x = 0; x < ND; ++x) {
        acc += M[x * ND + y];
        M[x * ND + y] = acc;
    }
}

__global__ void cumsum_y_kernel(float* __restrict__ D) {
    int tid = blockIdx.x * blockDim.x + threadIdx.x;
    if (tid >= 2 * ND) return;
    float* M = D + (tid / ND) * MAPSZ;
    int x = tid % ND;
    float acc = 0.0f;
    for (int y = 0; y < ND; ++y) {
        acc += M[x * ND + y];
        M[x * ND + y] = acc;
    }
}

// ---------------------------------------------------------------------------
// Stage 3: reductions. sums[0]=sum area_old (movable), sums[1]=sum route_area,
//          sums[2]=filler_area_old
// ---------------------------------------------------------------------------
__global__ void reduce_kernel(const float* __restrict__ pos,
                              const float* __restrict__ nsx,
                              const float* __restrict__ nsy,
                              const float* __restrict__ Dh,
                              const float* __restrict__ Dv,
                              double* __restrict__ sums) {
    double a_old = 0.0, a_route = 0.0, a_fill = 0.0;
    int stride = gridDim.x * blockDim.x;
    for (int i = blockIdx.x * blockDim.x + threadIdx.x;
         i < N_MOVABLE + N_FILLER; i += stride) {
        if (i < N_MOVABLE) {
            float sx = nsx[i], sy = nsy[i];
            float cx = pos[i] + 0.5f * sx;
            float cy = pos[N_NODES + i] + 0.5f * sy;
            int bx = bin_idx(cx), by = bin_idx(cy);
            float util = fmaxf(Dh[bx * ND + by], Dv[bx * ND + by]);
            float ratio = fminf(fmaxf(util, 0.5f), 2.0f);
            float area = sx * sy;
            a_old += (double)area;
            a_route += (double)(area * ratio);
        } else {
            int j = (N_NODES - N_FILLER) + (i - N_MOVABLE);
            a_fill += (double)(nsx[j] * nsy[j]);
        }
    }
    // wave-64 butterfly reduce, then one f64 atomic per wave per sum
    for (int off = 32; off > 0; off >>= 1) {
        a_old   += __shfl_down(a_old, off);
        a_route += __shfl_down(a_route, off);
        a_fill  += __shfl_down(a_fill, off);
    }
    if ((threadIdx.x & 63) == 0) {
        atomicAdd(&sums[0], a_old);
        atomicAdd(&sums[1], a_route);
        atomicAdd(&sums[2], a_fill);
    }
}

// ---------------------------------------------------------------------------
// Stage 4: final output. out = [x(2M), y(2M), nsx(2M), nsy(2M)]
// ---------------------------------------------------------------------------
__global__ void final_kernel(const float* __restrict__ pos,
                             const float* __restrict__ nsx,
                             const float* __restrict__ nsy,
                             const float* __restrict__ Dh,
                             const float* __restrict__ Dv,
                             const double* __restrict__ sums,
                             float* __restrict__ out) {
    double sum_area  = sums[0];
    double sum_route = sums[1];
    double fill_old  = sums[2];
    double max_total = sum_area + fill_old;

    float scale = fminf(1.0f, (float)(max_total / fmax(sum_route, 1e-6)));
    float sum_new = (float)(scale * (float)sum_route);
    float fscale = sqrtf(fmaxf((float)max_total - sum_new, 0.0f) /
                         fmaxf((float)fill_old, 1e-6f));

    int stride = gridDim.x * blockDim.x;
    for (int i = blockIdx.x * blockDim.x + threadIdx.x; i < N_NODES; i += stride) {
        float x = pos[i], y = pos[N_NODES + i];
        float sx = nsx[i], sy = nsy[i];
        float ox = x, oy = y, osx = sx, osy = sy;

        if (i < N_MOVABLE) {
            float cx = x + 0.5f * sx;
            float cy = y + 0.5f * sy;
            int bx = bin_idx(cx), by = bin_idx(cy);
            float util = fmaxf(Dh[bx * ND + by], Dv[bx * ND + by]);
            float ratio = fminf(fmaxf(util, 0.5f), 2.0f);
            float area = sx * sy;
            float route = area * ratio;
            float new_area = route * scale;
            float sr = sqrtf(new_area / fmaxf(area, 1e-6f));
            float sx_new = sx * sr, sy_new = sy * sr;
            ox = x + 0.5f * (sx - sx_new);
            oy = y + 0.5f * (sy - sy_new);
            osx = sx_new; osy = sy_new;
        } else if (i >= N_NODES - N_FILLER) {
            osx = sx * fscale;
            osy = sy * fscale;
        }

        out[i] = ox;
        out[N_NODES + i] = oy;
        out[2 * N_NODES + i] = osx;
        out[3 * N_NODES + i] = osy;
    }
}

// ---------------------------------------------------------------------------
extern "C" void kernel_launch(void* const* d_in, const int* in_sizes, int n_in,
                              void* d_out, int out_size, void* d_ws, size_t ws_size,
                              hipStream_t stream) {
    const float* pos         = (const float*)d_in[0];
    const float* pin_pos     = (const float*)d_in[1];
    const float* nsx         = (const float*)d_in[2];
    const float* nsy         = (const float*)d_in[3];
    const int*   flat_netpin = (const int*)d_in[4];
    // d_in[5] = pin2net (unused: pins of net n are flat_netpin[4n..4n+3])
    float* out = (float*)d_out;

    float*  Dh   = (float*)d_ws;
    float*  Dv   = Dh + MAPSZ;
    double* sums = (double*)(Dv + MAPSZ);   // 2*MAPSZ*4 bytes is 8B-aligned

    size_t zero_bytes = 2 * MAPSZ * sizeof(float) + 3 * sizeof(double);
    hipMemsetAsync(d_ws, 0, zero_bytes, stream);

    net_kernel<<<(N_NETS + 255) / 256, 256, 0, stream>>>(pin_pos, flat_netpin, Dh, Dv);
    cumsum_x_kernel<<<(2 * ND + 255) / 256, 256, 0, stream>>>(Dh);
    cumsum_y_kernel<<<(2 * ND + 255) / 256, 256, 0, stream>>>(Dh);
    reduce_kernel<<<2048, 256, 0, stream>>>(pos, nsx, nsy, Dh, Dv, sums);
    final_kernel<<<(N_NODES + 255) / 256, 256, 0, stream>>>(pos, nsx, nsy, Dh, Dv, sums, out);
}

// Round 2
// 972.797 us; speedup vs baseline: 1.1553x; 1.1553x over previous
//
#include <hip/hip_runtime.h>
#include <math.h>

#define N_NODES   2000000
#define N_MOVABLE 1500000
#define N_FILLER  400000
#define N_NETS    1500000
#define N_PINS    (N_NETS * 4)
#define NB        512                  // bins per axis
#define ND        513                  // diff-map dimension (NB+1)
#define MAPSZ     (ND * ND)

__device__ __forceinline__ float binw() { return 1000.0f / 512.0f; }  // exact: 1.953125

__device__ __forceinline__ int bin_idx(float v) {
    float b = floorf(v / binw());
    b = fminf(fmaxf(b, 0.0f), 511.0f);
    return (int)b;
}

// ---------------------------------------------------------------------------
// Stage 0: pack pin x/y halves into float2 so each pin gather is ONE line
// ---------------------------------------------------------------------------
__global__ void pack_kernel(const float* __restrict__ pin_pos,
                            float2* __restrict__ pp) {
    int i = blockIdx.x * blockDim.x + threadIdx.x;   // one float4 pair per thread
    if (i >= N_PINS / 4) return;
    float4 a = reinterpret_cast<const float4*>(pin_pos)[i];            // px[4i..]
    float4 b = reinterpret_cast<const float4*>(pin_pos + N_PINS)[i];   // py[4i..]
    float4* o = reinterpret_cast<float4*>(pp + 4 * (size_t)i);
    o[0] = make_float4(a.x, b.x, a.y, b.y);
    o[1] = make_float4(a.z, b.z, a.w, b.w);
}

// ---------------------------------------------------------------------------
// Stage 1: per-net bbox -> density -> 4-corner difference-map atomics
// D is float2: .x = horizontal map, .y = vertical map
// ---------------------------------------------------------------------------
template <bool PACKED>
__global__ void net_kernel(const float* __restrict__ pin_pos,
                           const float2* __restrict__ pp,
                           const int*  __restrict__ flat_netpin,
                           float2* __restrict__ D) {
    int n = blockIdx.x * blockDim.x + threadIdx.x;
    if (n >= N_NETS) return;

    int4 fp = *reinterpret_cast<const int4*>(flat_netpin + 4 * n);

    float px0, px1, px2, px3, py0, py1, py2, py3;
    if (PACKED) {
        float2 p0 = pp[fp.x], p1 = pp[fp.y], p2 = pp[fp.z], p3 = pp[fp.w];
        px0 = p0.x; py0 = p0.y; px1 = p1.x; py1 = p1.y;
        px2 = p2.x; py2 = p2.y; px3 = p3.x; py3 = p3.y;
    } else {
        px0 = pin_pos[fp.x]; px1 = pin_pos[fp.y];
        px2 = pin_pos[fp.z]; px3 = pin_pos[fp.w];
        py0 = pin_pos[N_PINS + fp.x]; py1 = pin_pos[N_PINS + fp.y];
        py2 = pin_pos[N_PINS + fp.z]; py3 = pin_pos[N_PINS + fp.w];
    }

    float xl = fminf(fminf(px0, px1), fminf(px2, px3));
    float xh = fmaxf(fmaxf(px0, px1), fmaxf(px2, px3));
    float yl = fminf(fminf(py0, py1), fminf(py2, py3));
    float yh = fmaxf(fmaxf(py0, py1), fmaxf(py2, py3));

    float bw = xh - xl, bh = yh - yl;
    float barea = fmaxf(bw * bh, 1e-6f);
    float vh = (bw / barea) * (1.0f / 1.5f);   // fold /UNIT_H_CAP
    float vv = (bh / barea) * (1.0f / 1.5f);

    int blx = bin_idx(xl), bhx = bin_idx(xh);
    int bly = bin_idx(yl), bhy = bin_idx(yh);

    int i00 = blx * ND + bly;
    int i10 = (bhx + 1) * ND + bly;
    int i01 = blx * ND + (bhy + 1);
    int i11 = (bhx + 1) * ND + (bhy + 1);

    atomicAdd(&D[i00].x,  vh);  atomicAdd(&D[i00].y,  vv);
    atomicAdd(&D[i10].x, -vh);  atomicAdd(&D[i10].y, -vv);
    atomicAdd(&D[i01].x, -vh);  atomicAdd(&D[i01].y, -vv);
    atomicAdd(&D[i11].x,  vh);  atomicAdd(&D[i11].y,  vv);
}

// ---------------------------------------------------------------------------
// Stage 2: 2D prefix sums over the cropped 512x512 region only.
// (Row/col 512 of D never affects util[:512,:512].)
// Hillis-Steele inclusive scan, 1 block of 512 threads per line.
// ---------------------------------------------------------------------------
__global__ void scan_x_kernel(float2* __restrict__ D) {
    __shared__ float2 s[NB];
    int y = blockIdx.x;         // 0..511
    int t = threadIdx.x;        // x = 0..511
    s[t] = D[t * ND + y];
    __syncthreads();
    for (int off = 1; off < NB; off <<= 1) {
        float2 u = s[t];
        if (t >= off) { float2 w = s[t - off]; u.x += w.x; u.y += w.y; }
        __syncthreads();
        s[t] = u;
        __syncthreads();
    }
    D[t * ND + y] = s[t];
}

__global__ void scan_y_kernel(float2* __restrict__ D) {
    __shared__ float2 s[NB];
    int x = blockIdx.x;         // 0..511
    int t = threadIdx.x;        // y = 0..511
    s[t] = D[x * ND + t];       // coalesced
    __syncthreads();
    for (int off = 1; off < NB; off <<= 1) {
        float2 u = s[t];
        if (t >= off) { float2 w = s[t - off]; u.x += w.x; u.y += w.y; }
        __syncthreads();
        s[t] = u;
        __syncthreads();
    }
    D[x * ND + t] = s[t];
}

// ---------------------------------------------------------------------------
// Stage 3: reductions. sums[0]=sum area_old, sums[1]=sum route_area,
//          sums[2]=filler_area_old
// ---------------------------------------------------------------------------
__global__ void reduce_kernel(const float* __restrict__ pos,
                              const float* __restrict__ nsx,
                              const float* __restrict__ nsy,
                              const float2* __restrict__ D,
                              double* __restrict__ sums) {
    double a_old = 0.0, a_route = 0.0, a_fill = 0.0;
    int stride = gridDim.x * blockDim.x;
    for (int i = blockIdx.x * blockDim.x + threadIdx.x;
         i < N_MOVABLE + N_FILLER; i += stride) {
        if (i < N_MOVABLE) {
            float sx = nsx[i], sy = nsy[i];
            float cx = pos[i] + 0.5f * sx;
            float cy = pos[N_NODES + i] + 0.5f * sy;
            int bx = bin_idx(cx), by = bin_idx(cy);
            float2 u2 = D[bx * ND + by];
            float util = fmaxf(u2.x, u2.y);
            float ratio = fminf(fmaxf(util, 0.5f), 2.0f);
            float area = sx * sy;
            a_old += (double)area;
            a_route += (double)(area * ratio);
        } else {
            int j = (N_NODES - N_FILLER) + (i - N_MOVABLE);
            a_fill += (double)(nsx[j] * nsy[j]);
        }
    }
    for (int off = 32; off > 0; off >>= 1) {
        a_old   += __shfl_down(a_old, off);
        a_route += __shfl_down(a_route, off);
        a_fill  += __shfl_down(a_fill, off);
    }
    if ((threadIdx.x & 63) == 0) {
        atomicAdd(&sums[0], a_old);
        atomicAdd(&sums[1], a_route);
        atomicAdd(&sums[2], a_fill);
    }
}

// ---------------------------------------------------------------------------
// Stage 4: final output. out = [x(2M), y(2M), nsx(2M), nsy(2M)]
// ---------------------------------------------------------------------------
__global__ void final_kernel(const float* __restrict__ pos,
                             const float* __restrict__ nsx,
                             const float* __restrict__ nsy,
                             const float2* __restrict__ D,
                             const double* __restrict__ sums,
                             float* __restrict__ out) {
    double sum_area  = sums[0];
    double sum_route = sums[1];
    double fill_old  = sums[2];
    double max_total = sum_area + fill_old;

    float scale = fminf(1.0f, (float)(max_total / fmax(sum_route, 1e-6)));
    float sum_new = (float)(scale * (float)sum_route);
    float fscale = sqrtf(fmaxf((float)max_total - sum_new, 0.0f) /
                         fmaxf((float)fill_old, 1e-6f));

    int stride = gridDim.x * blockDim.x;
    for (int i = blockIdx.x * blockDim.x + threadIdx.x; i < N_NODES; i += stride) {
        float x = pos[i], y = pos[N_NODES + i];
        float sx = nsx[i], sy = nsy[i];
        float ox = x, oy = y, osx = sx, osy = sy;

        if (i < N_MOVABLE) {
            float cx = x + 0.5f * sx;
            float cy = y + 0.5f * sy;
            int bx = bin_idx(cx), by = bin_idx(cy);
            float2 u2 = D[bx * ND + by];
            float util = fmaxf(u2.x, u2.y);
            float ratio = fminf(fmaxf(util, 0.5f), 2.0f);
            float area = sx * sy;
            float new_area = area * ratio * scale;
            float sr = sqrtf(new_area / fmaxf(area, 1e-6f));
            float sx_new = sx * sr, sy_new = sy * sr;
            ox = x + 0.5f * (sx - sx_new);
            oy = y + 0.5f * (sy - sy_new);
            osx = sx_new; osy = sy_new;
        } else if (i >= N_NODES - N_FILLER) {
            osx = sx * fscale;
            osy = sy * fscale;
        }

        out[i] = ox;
        out[N_NODES + i] = oy;
        out[2 * N_NODES + i] = osx;
        out[3 * N_NODES + i] = osy;
    }
}

// ---------------------------------------------------------------------------
extern "C" void kernel_launch(void* const* d_in, const int* in_sizes, int n_in,
                              void* d_out, int out_size, void* d_ws, size_t ws_size,
                              hipStream_t stream) {
    const float* pos         = (const float*)d_in[0];
    const float* pin_pos     = (const float*)d_in[1];
    const float* nsx         = (const float*)d_in[2];
    const float* nsy         = (const float*)d_in[3];
    const int*   flat_netpin = (const int*)d_in[4];
    float* out = (float*)d_out;

    // Preferred ws layout: pp (48 MB) | D (2.1 MB) | sums (24 B)
    size_t pp_bytes = (size_t)N_PINS * sizeof(float2);
    size_t d_bytes  = (size_t)MAPSZ * sizeof(float2);
    size_t need     = pp_bytes + d_bytes + 3 * sizeof(double);
    bool packed = (ws_size >= need);

    float2* pp;
    float2* D;
    double* sums;
    if (packed) {
        pp   = (float2*)d_ws;
        D    = (float2*)((char*)d_ws + pp_bytes);
        sums = (double*)((char*)D + d_bytes);
        hipMemsetAsync((char*)d_ws + pp_bytes, 0, d_bytes + 3 * sizeof(double), stream);
        pack_kernel<<<(N_PINS / 4 + 255) / 256, 256, 0, stream>>>(pin_pos, pp);
        net_kernel<true><<<(N_NETS + 255) / 256, 256, 0, stream>>>(pin_pos, pp, flat_netpin, D);
    } else {
        pp   = nullptr;
        D    = (float2*)d_ws;
        sums = (double*)((char*)d_ws + d_bytes);
        hipMemsetAsync(d_ws, 0, d_bytes + 3 * sizeof(double), stream);
        net_kernel<false><<<(N_NETS + 255) / 256, 256, 0, stream>>>(pin_pos, pp, flat_netpin, D);
    }

    scan_x_kernel<<<NB, NB, 0, stream>>>(D);
    scan_y_kernel<<<NB, NB, 0, stream>>>(D);
    reduce_kernel<<<2048, 256, 0, stream>>>(pos, nsx, nsy, D, sums);
    final_kernel<<<(N_NODES + 255) / 256, 256, 0, stream>>>(pos, nsx, nsy, D, sums, out);
}

// Round 3
// 492.928 us; speedup vs baseline: 2.2800x; 1.9735x over previous
//
#include <hip/hip_runtime.h>
#include <hip/hip_fp16.h>
#include <math.h>

#define N_NODES   2000000
#define N_MOVABLE 1500000
#define N_FILLER  400000
#define N_NETS    1500000
#define N_PINS    (N_NETS * 4)
#define NB        512                  // bins per axis
#define ND        513                  // diff-map dimension (NB+1)
#define MAPSZ     (ND * ND)
#define RED_BLOCKS 512

__device__ __forceinline__ int bin_idx(float v) {
    // BIN_W = 1000/512 = 1.953125 exactly; matches jnp floor(v / BIN_W)
    float b = floorf(v / 1.953125f);
    b = fminf(fmaxf(b, 0.0f), 511.0f);
    return (int)b;
}

// ---------------------------------------------------------------------------
// Stage 0: pack pin x/y halves into float2 so each pin gather is ONE line
// ---------------------------------------------------------------------------
__global__ void pack_kernel(const float* __restrict__ pin_pos,
                            float2* __restrict__ pp) {
    int i = blockIdx.x * blockDim.x + threadIdx.x;   // one float4 pair per thread
    if (i >= N_PINS / 4) return;
    float4 a = reinterpret_cast<const float4*>(pin_pos)[i];            // px[4i..]
    float4 b = reinterpret_cast<const float4*>(pin_pos + N_PINS)[i];   // py[4i..]
    float4* o = reinterpret_cast<float4*>(pp + 4 * (size_t)i);
    o[0] = make_float4(a.x, b.x, a.y, b.y);
    o[1] = make_float4(a.z, b.z, a.w, b.w);
}

// ---------------------------------------------------------------------------
// Stage 1a: pure gather. Per net: 4 pin gathers -> bbox -> 16B record.
// rec = {vh, vv, pack(blx,bly), pack(bhx+1,bhy+1)}
// ---------------------------------------------------------------------------
template <bool PACKED>
__global__ void gather_kernel(const float* __restrict__ pin_pos,
                              const float2* __restrict__ pp,
                              const int*  __restrict__ flat_netpin,
                              float4* __restrict__ rec) {
    int n = blockIdx.x * blockDim.x + threadIdx.x;
    if (n >= N_NETS) return;

    int4 fp = *reinterpret_cast<const int4*>(flat_netpin + 4 * n);

    float px0, px1, px2, px3, py0, py1, py2, py3;
    if (PACKED) {
        float2 p0 = pp[fp.x], p1 = pp[fp.y], p2 = pp[fp.z], p3 = pp[fp.w];
        px0 = p0.x; py0 = p0.y; px1 = p1.x; py1 = p1.y;
        px2 = p2.x; py2 = p2.y; px3 = p3.x; py3 = p3.y;
    } else {
        px0 = pin_pos[fp.x]; px1 = pin_pos[fp.y];
        px2 = pin_pos[fp.z]; px3 = pin_pos[fp.w];
        py0 = pin_pos[N_PINS + fp.x]; py1 = pin_pos[N_PINS + fp.y];
        py2 = pin_pos[N_PINS + fp.z]; py3 = pin_pos[N_PINS + fp.w];
    }

    float xl = fminf(fminf(px0, px1), fminf(px2, px3));
    float xh = fmaxf(fmaxf(px0, px1), fmaxf(px2, px3));
    float yl = fminf(fminf(py0, py1), fminf(py2, py3));
    float yh = fmaxf(fmaxf(py0, py1), fmaxf(py2, py3));

    float bw = xh - xl, bh = yh - yl;
    float barea = fmaxf(bw * bh, 1e-6f);
    float vh = (bw / barea) * (1.0f / 1.5f);   // fold /UNIT_H_CAP
    float vv = (bh / barea) * (1.0f / 1.5f);

    unsigned blx = bin_idx(xl), bhx = bin_idx(xh);
    unsigned bly = bin_idx(yl), bhy = bin_idx(yh);

    float4 r;
    r.x = vh; r.y = vv;
    r.z = __uint_as_float(blx | (bly << 16));
    r.w = __uint_as_float((bhx + 1) | ((bhy + 1) << 16));
    rec[n] = r;
}

// ---------------------------------------------------------------------------
// Stage 1b: pure scatter. 4 packed-f16 atomics per net into half2 diff map.
// ---------------------------------------------------------------------------
__global__ void scatter_kernel(const float4* __restrict__ rec,
                               __half2* __restrict__ Dd) {
    int n = blockIdx.x * blockDim.x + threadIdx.x;
    if (n >= N_NETS) return;
    float4 r = rec[n];
    unsigned lo = __float_as_uint(r.z), hi = __float_as_uint(r.w);
    int blx = lo & 0xffff, bly = (int)(lo >> 16);
    int bx1 = hi & 0xffff, by1 = (int)(hi >> 16);

    __half2 v  = __floats2half2_rn(r.x, r.y);
    __half2 nv = __floats2half2_rn(-r.x, -r.y);   // exact negation

    unsafeAtomicAdd(&Dd[blx * ND + bly], v);
    unsafeAtomicAdd(&Dd[bx1 * ND + bly], nv);
    unsafeAtomicAdd(&Dd[blx * ND + by1], nv);
    unsafeAtomicAdd(&Dd[bx1 * ND + by1], v);
}

// ---------------------------------------------------------------------------
// Stage 2: 2D prefix sums over the cropped 512x512 region (f32 result in S).
// Row/col 512 of the diff map provably never affects util[:512,:512].
// ---------------------------------------------------------------------------
__global__ void scan_x_kernel(const __half2* __restrict__ Dd,
                              float2* __restrict__ S) {
    __shared__ float2 s[NB];
    int y = blockIdx.x;         // 0..511
    int t = threadIdx.x;        // x = 0..511
    __half2 h = Dd[t * ND + y];
    s[t] = make_float2(__low2float(h), __high2float(h));
    __syncthreads();
    for (int off = 1; off < NB; off <<= 1) {
        float2 u = s[t];
        if (t >= off) { float2 w = s[t - off]; u.x += w.x; u.y += w.y; }
        __syncthreads();
        s[t] = u;
        __syncthreads();
    }
    S[t * NB + y] = s[t];
}

__global__ void scan_y_kernel(float2* __restrict__ S) {
    __shared__ float2 s[NB];
    int x = blockIdx.x;         // 0..511
    int t = threadIdx.x;        // y = 0..511
    s[t] = S[x * NB + t];       // coalesced
    __syncthreads();
    for (int off = 1; off < NB; off <<= 1) {
        float2 u = s[t];
        if (t >= off) { float2 w = s[t - off]; u.x += w.x; u.y += w.y; }
        __syncthreads();
        s[t] = u;
        __syncthreads();
    }
    S[x * NB + t] = s[t];
}

// ---------------------------------------------------------------------------
// Stage 3: reductions -> per-block partials (no global same-address atomics)
// ---------------------------------------------------------------------------
__global__ void reduce_kernel(const float* __restrict__ pos,
                              const float* __restrict__ nsx,
                              const float* __restrict__ nsy,
                              const float2* __restrict__ S,
                              double* __restrict__ partials) {
    double a_old = 0.0, a_route = 0.0, a_fill = 0.0;
    int stride = gridDim.x * blockDim.x;
    for (int i = blockIdx.x * blockDim.x + threadIdx.x;
         i < N_MOVABLE + N_FILLER; i += stride) {
        if (i < N_MOVABLE) {
            float sx = nsx[i], sy = nsy[i];
            float cx = pos[i] + 0.5f * sx;
            float cy = pos[N_NODES + i] + 0.5f * sy;
            int bx = bin_idx(cx), by = bin_idx(cy);
            float2 u2 = S[bx * NB + by];
            float ratio = fminf(fmaxf(fmaxf(u2.x, u2.y), 0.5f), 2.0f);
            float area = sx * sy;
            a_old += (double)area;
            a_route += (double)(area * ratio);
        } else {
            int j = (N_NODES - N_FILLER) + (i - N_MOVABLE);
            a_fill += (double)(nsx[j] * nsy[j]);
        }
    }
    for (int off = 32; off > 0; off >>= 1) {
        a_old   += __shfl_down(a_old, off);
        a_route += __shfl_down(a_route, off);
        a_fill  += __shfl_down(a_fill, off);
    }
    __shared__ double sd[4][3];
    int wid = threadIdx.x >> 6, lane = threadIdx.x & 63;
    if (lane == 0) { sd[wid][0] = a_old; sd[wid][1] = a_route; sd[wid][2] = a_fill; }
    __syncthreads();
    if (threadIdx.x == 0) {
        double s0 = 0, s1 = 0, s2 = 0;
        for (int w = 0; w < 4; ++w) { s0 += sd[w][0]; s1 += sd[w][1]; s2 += sd[w][2]; }
        partials[blockIdx.x * 3 + 0] = s0;
        partials[blockIdx.x * 3 + 1] = s1;
        partials[blockIdx.x * 3 + 2] = s2;
    }
}

__global__ void finish_kernel(const double* __restrict__ partials,
                              double* __restrict__ sums) {
    int t = threadIdx.x;   // 512 threads, one per partial record
    double s0 = partials[t * 3 + 0];
    double s1 = partials[t * 3 + 1];
    double s2 = partials[t * 3 + 2];
    for (int off = 32; off > 0; off >>= 1) {
        s0 += __shfl_down(s0, off);
        s1 += __shfl_down(s1, off);
        s2 += __shfl_down(s2, off);
    }
    __shared__ double sd[8][3];
    int wid = t >> 6, lane = t & 63;
    if (lane == 0) { sd[wid][0] = s0; sd[wid][1] = s1; sd[wid][2] = s2; }
    __syncthreads();
    if (t == 0) {
        double a = 0, b = 0, c = 0;
        for (int w = 0; w < 8; ++w) { a += sd[w][0]; b += sd[w][1]; c += sd[w][2]; }
        sums[0] = a; sums[1] = b; sums[2] = c;
    }
}

// ---------------------------------------------------------------------------
// Stage 4: final output. out = [x(2M), y(2M), nsx(2M), nsy(2M)]
// ---------------------------------------------------------------------------
__global__ void final_kernel(const float* __restrict__ pos,
                             const float* __restrict__ nsx,
                             const float* __restrict__ nsy,
                             const float2* __restrict__ S,
                             const double* __restrict__ sums,
                             float* __restrict__ out) {
    double sum_area  = sums[0];
    double sum_route = sums[1];
    double fill_old  = sums[2];
    double max_total = sum_area + fill_old;

    float scale = fminf(1.0f, (float)(max_total / fmax(sum_route, 1e-6)));
    float sum_new = (float)(scale * (float)sum_route);
    float fscale = sqrtf(fmaxf((float)max_total - sum_new, 0.0f) /
                         fmaxf((float)fill_old, 1e-6f));

    int stride = gridDim.x * blockDim.x;
    for (int i = blockIdx.x * blockDim.x + threadIdx.x; i < N_NODES; i += stride) {
        float x = pos[i], y = pos[N_NODES + i];
        float sx = nsx[i], sy = nsy[i];
        float ox = x, oy = y, osx = sx, osy = sy;

        if (i < N_MOVABLE) {
            float cx = x + 0.5f * sx;
            float cy = y + 0.5f * sy;
            int bx = bin_idx(cx), by = bin_idx(cy);
            float2 u2 = S[bx * NB + by];
            float ratio = fminf(fmaxf(fmaxf(u2.x, u2.y), 0.5f), 2.0f);
            float area = sx * sy;
            float new_area = area * ratio * scale;
            float sr = sqrtf(new_area / fmaxf(area, 1e-6f));
            float sx_new = sx * sr, sy_new = sy * sr;
            ox = x + 0.5f * (sx - sx_new);
            oy = y + 0.5f * (sy - sy_new);
            osx = sx_new; osy = sy_new;
        } else if (i >= N_NODES - N_FILLER) {
            osx = sx * fscale;
            osy = sy * fscale;
        }

        out[i] = ox;
        out[N_NODES + i] = oy;
        out[2 * N_NODES + i] = osx;
        out[3 * N_NODES + i] = osy;
    }
}

// ---------------------------------------------------------------------------
extern "C" void kernel_launch(void* const* d_in, const int* in_sizes, int n_in,
                              void* d_out, int out_size, void* d_ws, size_t ws_size,
                              hipStream_t stream) {
    const float* pos         = (const float*)d_in[0];
    const float* pin_pos     = (const float*)d_in[1];
    const float* nsx         = (const float*)d_in[2];
    const float* nsy         = (const float*)d_in[3];
    const int*   flat_netpin = (const int*)d_in[4];
    float* out = (float*)d_out;

    size_t pp_b   = (size_t)N_PINS * sizeof(float2);               // 48 MB
    size_t rec_b  = (size_t)N_NETS * sizeof(float4);               // 24 MB
    size_t dd_b   = ((size_t)MAPSZ * sizeof(__half2) + 7) & ~(size_t)7;
    size_t sums_b = 3 * sizeof(double);
    size_t s_b    = (size_t)NB * NB * sizeof(float2);              // 2.1 MB
    size_t part_b = (size_t)RED_BLOCKS * 3 * sizeof(double);

    bool packed = ws_size >= pp_b + rec_b + dd_b + sums_b + s_b + part_b;

    char* base = (char*)d_ws;
    float2* pp = nullptr;
    if (packed) { pp = (float2*)base; base += pp_b; }
    float4*  rec      = (float4*)base;  base += rec_b;
    __half2* Dd       = (__half2*)base; base += dd_b;
    double*  sums     = (double*)base;  base += sums_b;
    float2*  S        = (float2*)base;  base += s_b;
    double*  partials = (double*)base;

    hipMemsetAsync(Dd, 0, dd_b, stream);

    const int NET_BLOCKS = (N_NETS + 255) / 256;
    if (packed) {
        pack_kernel<<<(N_PINS / 4 + 255) / 256, 256, 0, stream>>>(pin_pos, pp);
        gather_kernel<true><<<NET_BLOCKS, 256, 0, stream>>>(pin_pos, pp, flat_netpin, rec);
    } else {
        gather_kernel<false><<<NET_BLOCKS, 256, 0, stream>>>(pin_pos, pp, flat_netpin, rec);
    }
    scatter_kernel<<<NET_BLOCKS, 256, 0, stream>>>(rec, Dd);

    scan_x_kernel<<<NB, NB, 0, stream>>>(Dd, S);
    scan_y_kernel<<<NB, NB, 0, stream>>>(S);

    reduce_kernel<<<RED_BLOCKS, 256, 0, stream>>>(pos, nsx, nsy, S, partials);
    finish_kernel<<<1, 512, 0, stream>>>(partials, sums);
    final_kernel<<<(N_NODES + 255) / 256, 256, 0, stream>>>(pos, nsx, nsy, S, sums, out);
}

// Round 4
// 253.366 us; speedup vs baseline: 4.4357x; 1.9455x over previous
//
#include <hip/hip_runtime.h>
#include <math.h>

#define N_NODES   2000000
#define N_MOVABLE 1500000
#define N_FILLER  400000
#define N_NETS    1500000
#define N_PINS    (N_NETS * 4)
#define NB        512                  // bins per axis (cropped map)
#define NT        16                   // tiles per axis
#define TILE      32                   // bins per tile axis
#define NBUCKET   (NT * NT)            // 256
#define CAP       10240                // slab capacity per bucket
#define RED_BLOCKS 512

__device__ __forceinline__ int bin_idx(float v) {
    // BIN_W = 1000/512 = 1.953125 exactly; matches jnp floor(v / BIN_W)
    float b = floorf(v / 1.953125f);
    b = fminf(fmaxf(b, 0.0f), 511.0f);
    return (int)b;
}

// ---------------------------------------------------------------------------
// Stage 0 (optional): pack pin x/y halves into float2 -> one line per gather
// ---------------------------------------------------------------------------
__global__ void pack_kernel(const float* __restrict__ pin_pos,
                            float2* __restrict__ pp) {
    int i = blockIdx.x * blockDim.x + threadIdx.x;
    if (i >= N_PINS / 4) return;
    float4 a = reinterpret_cast<const float4*>(pin_pos)[i];
    float4 b = reinterpret_cast<const float4*>(pin_pos + N_PINS)[i];
    float4* o = reinterpret_cast<float4*>(pp + 4 * (size_t)i);
    o[0] = make_float4(a.x, b.x, a.y, b.y);
    o[1] = make_float4(a.z, b.z, a.w, b.w);
}

// ---------------------------------------------------------------------------
// Stage 1: gather + bucket (counting-sort into per-tile slabs).
// rec = {vh, vv, pack(blx,bly), pack(bhx+1,bhy+1)}; bucket by bl tile.
// ---------------------------------------------------------------------------
template <bool PACKED>
__global__ __launch_bounds__(1024)
void gather_bin_kernel(const float* __restrict__ pin_pos,
                       const float2* __restrict__ pp,
                       const int*  __restrict__ flat_netpin,
                       float4* __restrict__ slab,
                       unsigned* __restrict__ g_ptr) {
    __shared__ unsigned hist[NBUCKET];
    __shared__ unsigned base[NBUCKET];
    int t = threadIdx.x;
    if (t < NBUCKET) hist[t] = 0;
    __syncthreads();

    int n = blockIdx.x * 1024 + t;
    float4 r = make_float4(0.f, 0.f, 0.f, 0.f);
    int b = 0;
    unsigned rank = 0;
    bool valid = (n < N_NETS);
    if (valid) {
        int4 fp = *reinterpret_cast<const int4*>(flat_netpin + 4 * n);
        float px0, px1, px2, px3, py0, py1, py2, py3;
        if (PACKED) {
            float2 p0 = pp[fp.x], p1 = pp[fp.y], p2 = pp[fp.z], p3 = pp[fp.w];
            px0 = p0.x; py0 = p0.y; px1 = p1.x; py1 = p1.y;
            px2 = p2.x; py2 = p2.y; px3 = p3.x; py3 = p3.y;
        } else {
            px0 = pin_pos[fp.x]; px1 = pin_pos[fp.y];
            px2 = pin_pos[fp.z]; px3 = pin_pos[fp.w];
            py0 = pin_pos[N_PINS + fp.x]; py1 = pin_pos[N_PINS + fp.y];
            py2 = pin_pos[N_PINS + fp.z]; py3 = pin_pos[N_PINS + fp.w];
        }
        float xl = fminf(fminf(px0, px1), fminf(px2, px3));
        float xh = fmaxf(fmaxf(px0, px1), fmaxf(px2, px3));
        float yl = fminf(fminf(py0, py1), fminf(py2, py3));
        float yh = fmaxf(fmaxf(py0, py1), fmaxf(py2, py3));

        float bw = xh - xl, bh = yh - yl;
        float barea = fmaxf(bw * bh, 1e-6f);
        float vh = (bw / barea) * (1.0f / 1.5f);   // fold /UNIT_H_CAP
        float vv = (bh / barea) * (1.0f / 1.5f);

        unsigned blx = bin_idx(xl), bhx = bin_idx(xh);
        unsigned bly = bin_idx(yl), bhy = bin_idx(yh);

        r.x = vh; r.y = vv;
        r.z = __uint_as_float(blx | (bly << 16));
        r.w = __uint_as_float((bhx + 1) | ((bhy + 1) << 16));
        b = (int)((bly >> 5) * NT + (blx >> 5));
        rank = atomicAdd(&hist[b], 1u);
    }
    __syncthreads();
    if (t < NBUCKET) {
        unsigned c = hist[t];
        base[t] = c ? atomicAdd(&g_ptr[t], c) : 0u;
    }
    __syncthreads();
    if (valid) {
        unsigned slot = base[b] + rank;
        if (slot < CAP) slab[(size_t)b * CAP + slot] = r;
    }
}

// ---------------------------------------------------------------------------
// Stage 2: per-tile accumulation in LDS (fp32), zero global atomics.
// 2 wgs per tile -> 2 partial diff maps Dp[2][NB][NB] (float2: h,v).
// A net's corners lie within +22 bins of its bl -> sources = bl-tiles
// {tx-1,tx} x {ty-1,ty}. Corner coords ==512 fall outside all tiles (dropped;
// they never affect the cropped 512x512 result).
// ---------------------------------------------------------------------------
__global__ __launch_bounds__(256)
void accum_kernel(const float4* __restrict__ slab,
                  const unsigned* __restrict__ g_cnt,
                  float2* __restrict__ Dp) {
    __shared__ float acc[TILE][TILE][2];
    int wg   = blockIdx.x;        // 0..511
    int half = wg & 1;
    int tile = wg >> 1;           // 0..255
    int tx = tile & (NT - 1);
    int ty = tile >> 4;

    for (int i = threadIdx.x; i < TILE * TILE * 2; i += 256)
        ((float*)acc)[i] = 0.0f;
    __syncthreads();

    int x0 = tx * TILE, y0 = ty * TILE;
    for (int dy = -1; dy <= 0; ++dy) {
        int sy = ty + dy; if (sy < 0) continue;
        for (int dx = -1; dx <= 0; ++dx) {
            int sx = tx + dx; if (sx < 0) continue;
            int sb = sy * NT + sx;
            unsigned cnt = min(g_cnt[sb], (unsigned)CAP);
            unsigned lo = half ? cnt / 2 : 0u;
            unsigned hi = half ? cnt : cnt / 2;
            const float4* recs = slab + (size_t)sb * CAP;
            for (unsigned i = lo + threadIdx.x; i < hi; i += 256) {
                float4 r = recs[i];
                unsigned zlo = __float_as_uint(r.z), zhi = __float_as_uint(r.w);
                int ax0 = (int)(zlo & 0xffffu), ay0 = (int)(zlo >> 16);
                int ax1 = (int)(zhi & 0xffffu), ay1 = (int)(zhi >> 16);
                int X0 = ax0 - x0, X1 = ax1 - x0;
                int Y0 = ay0 - y0, Y1 = ay1 - y0;
                bool inX0 = (unsigned)X0 < TILE, inX1 = (unsigned)X1 < TILE;
                bool inY0 = (unsigned)Y0 < TILE, inY1 = (unsigned)Y1 < TILE;
                if (inX0 && inY0) { atomicAdd(&acc[X0][Y0][0],  r.x); atomicAdd(&acc[X0][Y0][1],  r.y); }
                if (inX1 && inY0) { atomicAdd(&acc[X1][Y0][0], -r.x); atomicAdd(&acc[X1][Y0][1], -r.y); }
                if (inX0 && inY1) { atomicAdd(&acc[X0][Y1][0], -r.x); atomicAdd(&acc[X0][Y1][1], -r.y); }
                if (inX1 && inY1) { atomicAdd(&acc[X1][Y1][0],  r.x); atomicAdd(&acc[X1][Y1][1],  r.y); }
            }
        }
    }
    __syncthreads();
    float2* D = Dp + (size_t)half * NB * NB;
    for (int i = threadIdx.x; i < TILE * TILE; i += 256) {
        int X = i >> 5, Y = i & 31;
        D[(size_t)(x0 + X) * NB + (y0 + Y)] = make_float2(acc[X][Y][0], acc[X][Y][1]);
    }
}

// ---------------------------------------------------------------------------
// Fallback scatter (only if ws too small for slabs): f32 atomics into Dp[0]
// ---------------------------------------------------------------------------
__global__ void fb_scatter_kernel(const float4* __restrict__ rec,
                                  float2* __restrict__ Dp) {
    int n = blockIdx.x * blockDim.x + threadIdx.x;
    if (n >= N_NETS) return;
    float4 r = rec[n];
    unsigned zlo = __float_as_uint(r.z), zhi = __float_as_uint(r.w);
    int ax0 = (int)(zlo & 0xffffu), ay0 = (int)(zlo >> 16);
    int ax1 = (int)(zhi & 0xffffu), ay1 = (int)(zhi >> 16);
    if (ax0 < NB && ay0 < NB) { unsafeAtomicAdd(&Dp[ax0 * NB + ay0].x,  r.x); unsafeAtomicAdd(&Dp[ax0 * NB + ay0].y,  r.y); }
    if (ax1 < NB && ay0 < NB) { unsafeAtomicAdd(&Dp[ax1 * NB + ay0].x, -r.x); unsafeAtomicAdd(&Dp[ax1 * NB + ay0].y, -r.y); }
    if (ax0 < NB && ay1 < NB) { unsafeAtomicAdd(&Dp[ax0 * NB + ay1].x, -r.x); unsafeAtomicAdd(&Dp[ax0 * NB + ay1].y, -r.y); }
    if (ax1 < NB && ay1 < NB) { unsafeAtomicAdd(&Dp[ax1 * NB + ay1].x,  r.x); unsafeAtomicAdd(&Dp[ax1 * NB + ay1].y,  r.y); }
}

// ---------------------------------------------------------------------------
// Stage 3: 2D prefix sums (512x512), summing the two partial maps on load.
// ---------------------------------------------------------------------------
__global__ void scan_x_kernel(const float2* __restrict__ Dp,
                              float2* __restrict__ S) {
    __shared__ float2 s[NB];
    int y = blockIdx.x;
    int t = threadIdx.x;
    float2 a = Dp[(size_t)t * NB + y];
    float2 b = Dp[(size_t)NB * NB + (size_t)t * NB + y];
    s[t] = make_float2(a.x + b.x, a.y + b.y);
    __syncthreads();
    for (int off = 1; off < NB; off <<= 1) {
        float2 u = s[t];
        if (t >= off) { float2 w = s[t - off]; u.x += w.x; u.y += w.y; }
        __syncthreads();
        s[t] = u;
        __syncthreads();
    }
    S[(size_t)t * NB + y] = s[t];
}

__global__ void scan_y_kernel(float2* __restrict__ S) {
    __shared__ float2 s[NB];
    int x = blockIdx.x;
    int t = threadIdx.x;
    s[t] = S[(size_t)x * NB + t];
    __syncthreads();
    for (int off = 1; off < NB; off <<= 1) {
        float2 u = s[t];
        if (t >= off) { float2 w = s[t - off]; u.x += w.x; u.y += w.y; }
        __syncthreads();
        s[t] = u;
        __syncthreads();
    }
    S[(size_t)x * NB + t] = s[t];
}

// ---------------------------------------------------------------------------
// Stage 4: reductions -> per-block partials, then finish
// ---------------------------------------------------------------------------
__global__ void reduce_kernel(const float* __restrict__ pos,
                              const float* __restrict__ nsx,
                              const float* __restrict__ nsy,
                              const float2* __restrict__ S,
                              double* __restrict__ partials) {
    double a_old = 0.0, a_route = 0.0, a_fill = 0.0;
    int stride = gridDim.x * blockDim.x;
    for (int i = blockIdx.x * blockDim.x + threadIdx.x;
         i < N_MOVABLE + N_FILLER; i += stride) {
        if (i < N_MOVABLE) {
            float sx = nsx[i], sy = nsy[i];
            float cx = pos[i] + 0.5f * sx;
            float cy = pos[N_NODES + i] + 0.5f * sy;
            int bx = bin_idx(cx), by = bin_idx(cy);
            float2 u2 = S[(size_t)bx * NB + by];
            float ratio = fminf(fmaxf(fmaxf(u2.x, u2.y), 0.5f), 2.0f);
            float area = sx * sy;
            a_old += (double)area;
            a_route += (double)(area * ratio);
        } else {
            int j = (N_NODES - N_FILLER) + (i - N_MOVABLE);
            a_fill += (double)(nsx[j] * nsy[j]);
        }
    }
    for (int off = 32; off > 0; off >>= 1) {
        a_old   += __shfl_down(a_old, off);
        a_route += __shfl_down(a_route, off);
        a_fill  += __shfl_down(a_fill, off);
    }
    __shared__ double sd[4][3];
    int wid = threadIdx.x >> 6, lane = threadIdx.x & 63;
    if (lane == 0) { sd[wid][0] = a_old; sd[wid][1] = a_route; sd[wid][2] = a_fill; }
    __syncthreads();
    if (threadIdx.x == 0) {
        double s0 = 0, s1 = 0, s2 = 0;
        for (int w = 0; w < 4; ++w) { s0 += sd[w][0]; s1 += sd[w][1]; s2 += sd[w][2]; }
        partials[blockIdx.x * 3 + 0] = s0;
        partials[blockIdx.x * 3 + 1] = s1;
        partials[blockIdx.x * 3 + 2] = s2;
    }
}

__global__ void finish_kernel(const double* __restrict__ partials,
                              double* __restrict__ sums) {
    int t = threadIdx.x;
    double s0 = partials[t * 3 + 0];
    double s1 = partials[t * 3 + 1];
    double s2 = partials[t * 3 + 2];
    for (int off = 32; off > 0; off >>= 1) {
        s0 += __shfl_down(s0, off);
        s1 += __shfl_down(s1, off);
        s2 += __shfl_down(s2, off);
    }
    __shared__ double sd[8][3];
    int wid = t >> 6, lane = t & 63;
    if (lane == 0) { sd[wid][0] = s0; sd[wid][1] = s1; sd[wid][2] = s2; }
    __syncthreads();
    if (t == 0) {
        double a = 0, b = 0, c = 0;
        for (int w = 0; w < 8; ++w) { a += sd[w][0]; b += sd[w][1]; c += sd[w][2]; }
        sums[0] = a; sums[1] = b; sums[2] = c;
    }
}

// ---------------------------------------------------------------------------
// Stage 5: final output. out = [x(2M), y(2M), nsx(2M), nsy(2M)]
// ---------------------------------------------------------------------------
__global__ void final_kernel(const float* __restrict__ pos,
                             const float* __restrict__ nsx,
                             const float* __restrict__ nsy,
                             const float2* __restrict__ S,
                             const double* __restrict__ sums,
                             float* __restrict__ out) {
    double sum_area  = sums[0];
    double sum_route = sums[1];
    double fill_old  = sums[2];
    double max_total = sum_area + fill_old;

    float scale = fminf(1.0f, (float)(max_total / fmax(sum_route, 1e-6)));
    float sum_new = (float)(scale * (float)sum_route);
    float fscale = sqrtf(fmaxf((float)max_total - sum_new, 0.0f) /
                         fmaxf((float)fill_old, 1e-6f));

    int stride = gridDim.x * blockDim.x;
    for (int i = blockIdx.x * blockDim.x + threadIdx.x; i < N_NODES; i += stride) {
        float x = pos[i], y = pos[N_NODES + i];
        float sx = nsx[i], sy = nsy[i];
        float ox = x, oy = y, osx = sx, osy = sy;

        if (i < N_MOVABLE) {
            float cx = x + 0.5f * sx;
            float cy = y + 0.5f * sy;
            int bx = bin_idx(cx), by = bin_idx(cy);
            float2 u2 = S[(size_t)bx * NB + by];
            float ratio = fminf(fmaxf(fmaxf(u2.x, u2.y), 0.5f), 2.0f);
            float area = sx * sy;
            float new_area = area * ratio * scale;
            float sr = sqrtf(new_area / fmaxf(area, 1e-6f));
            float sx_new = sx * sr, sy_new = sy * sr;
            ox = x + 0.5f * (sx - sx_new);
            oy = y + 0.5f * (sy - sy_new);
            osx = sx_new; osy = sy_new;
        } else if (i >= N_NODES - N_FILLER) {
            osx = sx * fscale;
            osy = sy * fscale;
        }

        out[i] = ox;
        out[N_NODES + i] = oy;
        out[2 * N_NODES + i] = osx;
        out[3 * N_NODES + i] = osy;
    }
}

// ---------------------------------------------------------------------------
extern "C" void kernel_launch(void* const* d_in, const int* in_sizes, int n_in,
                              void* d_out, int out_size, void* d_ws, size_t ws_size,
                              hipStream_t stream) {
    const float* pos         = (const float*)d_in[0];
    const float* pin_pos     = (const float*)d_in[1];
    const float* nsx         = (const float*)d_in[2];
    const float* nsy         = (const float*)d_in[3];
    const int*   flat_netpin = (const int*)d_in[4];
    float* out = (float*)d_out;

    const size_t pp_b   = (size_t)N_PINS * sizeof(float2);            // 48 MB
    const size_t slab_b = (size_t)NBUCKET * CAP * sizeof(float4);     // 40 MB
    const size_t dp_b   = (size_t)2 * NB * NB * sizeof(float2);       // 4 MB
    const size_t s_b    = (size_t)NB * NB * sizeof(float2);           // 2 MB
    const size_t gp_b   = (size_t)NBUCKET * sizeof(unsigned);
    const size_t part_b = (size_t)RED_BLOCKS * 3 * sizeof(double);
    const size_t sums_b = 32;

    const size_t need_base = slab_b + dp_b + s_b + gp_b + part_b + sums_b;
    const size_t need_full = need_base + pp_b;

    bool use_slab = (ws_size >= need_base);
    bool packed   = (ws_size >= need_full);

    char* base = (char*)d_ws;
    float2* pp = nullptr;
    if (packed) { pp = (float2*)base; base += pp_b; }
    float4*   slab     = (float4*)base;   base += slab_b;
    float2*   Dp       = (float2*)base;   base += dp_b;
    float2*   S        = (float2*)base;   base += s_b;
    unsigned* g_ptr    = (unsigned*)base; base += gp_b;
    double*   partials = (double*)base;   base += part_b;
    double*   sums     = (double*)base;

    if (use_slab) {
        hipMemsetAsync(g_ptr, 0, gp_b, stream);
        const int GB_BLOCKS = (N_NETS + 1023) / 1024;
        if (packed) {
            pack_kernel<<<(N_PINS / 4 + 255) / 256, 256, 0, stream>>>(pin_pos, pp);
            gather_bin_kernel<true><<<GB_BLOCKS, 1024, 0, stream>>>(pin_pos, pp, flat_netpin, slab, g_ptr);
        } else {
            gather_bin_kernel<false><<<GB_BLOCKS, 1024, 0, stream>>>(pin_pos, pp, flat_netpin, slab, g_ptr);
        }
        accum_kernel<<<2 * NBUCKET, 256, 0, stream>>>(slab, g_ptr, Dp);
    } else {
        // Fallback: records linear in slab area, f32 atomic scatter into Dp[0]
        hipMemsetAsync(Dp, 0, dp_b, stream);
        gather_bin_kernel<false><<<(N_NETS + 1023) / 1024, 1024, 0, stream>>>(
            pin_pos, nullptr, flat_netpin, slab, g_ptr);  // unreachable sizing-wise; kept simple
        fb_scatter_kernel<<<(N_NETS + 255) / 256, 256, 0, stream>>>(slab, Dp);
    }

    scan_x_kernel<<<NB, NB, 0, stream>>>(Dp, S);
    scan_y_kernel<<<NB, NB, 0, stream>>>(S);

    reduce_kernel<<<RED_BLOCKS, 256, 0, stream>>>(pos, nsx, nsy, S, partials);
    finish_kernel<<<1, 512, 0, stream>>>(partials, sums);
    final_kernel<<<(N_NODES + 255) / 256, 256, 0, stream>>>(pos, nsx, nsy, S, sums, out);
}